// Round 7
// baseline (531.055 us; speedup 1.0000x reference)
//
#include <hip/hip_runtime.h>

#define NEG_INF_F (-1.0e9f)

typedef short bf16x8 __attribute__((ext_vector_type(8)));
typedef float f32x4 __attribute__((ext_vector_type(4)));

__device__ inline unsigned short bf_rne(float f) {
    unsigned u = __builtin_bit_cast(unsigned, f);
    u = (u + 0x7fffu + ((u >> 16) & 1u)) >> 16;
    return (unsigned short)u;
}
__device__ inline float bf_to_f32(unsigned short h) {
    unsigned u = ((unsigned)h) << 16;
    return __builtin_bit_cast(float, u);
}

// async global->LDS, 16B per lane; LDS dest = wave-uniform base + lane*16
__device__ inline void gload16(const unsigned short* g, unsigned short* l) {
    __builtin_amdgcn_global_load_lds(
        (const __attribute__((address_space(1))) unsigned int*)g,
        (__attribute__((address_space(3))) unsigned int*)l, 16, 0, 0);
}

// Swizzled fragment reads.
// frag32: [256][32]-bf16 quarter, chunk swizzle ^((r>>1)&3)
__device__ inline bf16x8 frag32(const unsigned short* t, int r, int ch) {
    return *reinterpret_cast<const bf16x8*>(&t[r * 32 + (ch ^ ((r >> 1) & 3)) * 8]);
}
// frag64: [256][64]-bf16 tile, chunk swizzle ^(r&7)
__device__ inline bf16x8 frag64(const unsigned short* t, int r, int ch) {
    return *reinterpret_cast<const bf16x8*>(&t[r * 64 + (ch ^ (r & 7)) * 8]);
}

// Stage one [256][32] quarter (16KB): 2 gload16 per wave.
__device__ inline void stage_q32(const unsigned short* __restrict__ g0, int ldg, int k0,
                                 unsigned short* qbuf, int w, int lane) {
#pragma unroll
    for (int c = 0; c < 2; ++c) {
        const int r = c * 128 + w * 16 + (lane >> 2);
        const int co = ((lane & 3) ^ ((r >> 1) & 3)) * 8;
        gload16(g0 + (long long)r * ldg + k0 + co, qbuf + (c * 128 + w * 16) * 32);
    }
}
// Stage two 64-row groups (c0,c1) of a [256][64] tile: 2 gload16 per wave.
__device__ inline void stage_h64(const unsigned short* __restrict__ g0, int ldg, int k0,
                                 unsigned short* base, int w, int lane, int c0, int c1) {
#pragma unroll
    for (int cc = 0; cc < 2; ++cc) {
        const int c = cc ? c1 : c0;
        const int r = c * 64 + w * 8 + (lane >> 3);
        const int co = ((lane & 7) ^ (r & 7)) * 8;
        gload16(g0 + (long long)r * ldg + k0 + co, base + (c * 64 + w * 8) * 64);
    }
}
// Stage full [256][64] tile: 4 gload16 per wave.
__device__ inline void stage_full64(const unsigned short* __restrict__ g0, int ldg, int k0,
                                    unsigned short* base, int w, int lane) {
#pragma unroll
    for (int c = 0; c < 4; ++c) {
        const int r = c * 64 + w * 8 + (lane >> 3);
        const int co = ((lane & 7) ^ (r & 7)) * 8;
        gload16(g0 + (long long)r * ldg + k0 + co, base + (c * 64 + w * 8) * 64);
    }
}

#define VMW6() asm volatile("s_waitcnt vmcnt(6)" ::: "memory")
#define VMW4() asm volatile("s_waitcnt vmcnt(4)" ::: "memory")
#define VMW2() asm volatile("s_waitcnt vmcnt(2)" ::: "memory")
#define VMW0() asm volatile("s_waitcnt vmcnt(0)" ::: "memory")
#define BAR()  __builtin_amdgcn_s_barrier()

// ---------------- 256x256 8-wave GEMM, phase-segmented counted-vmcnt ----------------
// C = A * B^T. TERMS: 3 = split hi/lo (Ah*Bh+Al*Bh+Ah*Bl), BK=32;
//              1 = hi only, BK=64.
// OMODE: 0 = f32 C (+ optional NEG_INF*mask[col]); 1 = split bf16 (Ch,Cl);
//        3 = bf16 transposed V^T store Ch[b2][col][s].
// LDS: 2 x 64KB buffers. TERMS=3 quarters: Ah@0, Al@8192, Bh@16384, Bl@24576 (ushorts).
// TERMS=1: A@0, B@16384. Loads never drain to 0 in steady state (counted vmcnt).
template <int TERMS, int OMODE>
__global__ __launch_bounds__(512, 2) void mfma_gemm256(
    const unsigned short* __restrict__ Ah_g, const unsigned short* __restrict__ Al_g,
    long long strideA, int lda,
    const unsigned short* __restrict__ Bh_g, const unsigned short* __restrict__ Bl_g,
    long long strideB, int ldb,
    float* __restrict__ Cf, unsigned short* __restrict__ Ch, unsigned short* __restrict__ Cl,
    long long strideC, int ldc, int K,
    const int* __restrict__ mask, long long strideMask)
{
    constexpr int KT = (TERMS == 3) ? 32 : 64;
    const int b = blockIdx.z;
    const int tid = threadIdx.x;
    const int w = tid >> 6, lane = tid & 63;
    const int wr = w >> 2, wc = w & 3;
    const int lr = lane & 15, lg = lane >> 4;
    const int rowBase = blockIdx.x * 256;
    const int colBase = blockIdx.y * 256;

    __shared__ unsigned short smem[65536];  // 128 KB: 2 x 64KB buffers

    const unsigned short* Ah0 = Ah_g + (long long)b * strideA + (long long)rowBase * lda;
    const unsigned short* Bh0 = Bh_g + (long long)b * strideB + (long long)colBase * ldb;
    const unsigned short* Al0 = (TERMS == 3)
        ? Al_g + (long long)b * strideA + (long long)rowBase * lda : nullptr;
    const unsigned short* Bl0 = (TERMS == 3)
        ? Bl_g + (long long)b * strideB + (long long)colBase * ldb : nullptr;

    f32x4 acc[8][4] = {};
    const int NT = K / KT;

    if constexpr (TERMS == 3) {
        // prologue: full tile 0, hi quarters first
        stage_q32(Ah0, lda, 0, smem + 0,     w, lane);
        stage_q32(Bh0, ldb, 0, smem + 16384, w, lane);
        stage_q32(Al0, lda, 0, smem + 8192,  w, lane);
        stage_q32(Bl0, ldb, 0, smem + 24576, w, lane);
        VMW4(); BAR();

        for (int t = 0; t < NT; ++t) {
            const unsigned short* cbuf = smem + (t & 1) * 32768;
            unsigned short* nbuf = smem + ((t + 1) & 1) * 32768;
            const int k1 = (t + 1) * KT;
            const bool more = (t + 1 < NT);

            // ---- segment 1: hi*hi ----
            if (more) {
                stage_q32(Ah0, lda, k1, nbuf + 0,     w, lane);
                stage_q32(Bh0, ldb, k1, nbuf + 16384, w, lane);
            }
            bf16x8 bh[4], ah0[4], ah1[4];
#pragma unroll
            for (int j = 0; j < 4; ++j) bh[j] = frag32(cbuf + 16384, wc * 64 + j * 16 + lr, lg);
#pragma unroll
            for (int f = 0; f < 4; ++f) ah0[f] = frag32(cbuf, wr * 128 + f * 16 + lr, lg);
            __builtin_amdgcn_s_setprio(1);
#pragma unroll
            for (int f = 0; f < 4; ++f)
#pragma unroll
                for (int j = 0; j < 4; ++j)
                    acc[f][j] = __builtin_amdgcn_mfma_f32_16x16x32_bf16(ah0[f], bh[j], acc[f][j], 0, 0, 0);
            __builtin_amdgcn_s_setprio(0);
#pragma unroll
            for (int f = 0; f < 4; ++f) ah1[f] = frag32(cbuf, wr * 128 + 64 + f * 16 + lr, lg);
            __builtin_amdgcn_s_setprio(1);
#pragma unroll
            for (int f = 0; f < 4; ++f)
#pragma unroll
                for (int j = 0; j < 4; ++j)
                    acc[4 + f][j] = __builtin_amdgcn_mfma_f32_16x16x32_bf16(ah1[f], bh[j], acc[4 + f][j], 0, 0, 0);
            __builtin_amdgcn_s_setprio(0);
            if (more) { VMW6(); } else { VMW2(); }
            BAR();

            // ---- segment 2: lo*hi ----
            if (more) stage_q32(Al0, lda, k1, nbuf + 8192, w, lane);
            {
                bf16x8 al[4];
#pragma unroll
                for (int f = 0; f < 4; ++f) al[f] = frag32(cbuf + 8192, wr * 128 + f * 16 + lr, lg);
                __builtin_amdgcn_s_setprio(1);
#pragma unroll
                for (int f = 0; f < 4; ++f)
#pragma unroll
                    for (int j = 0; j < 4; ++j)
                        acc[f][j] = __builtin_amdgcn_mfma_f32_16x16x32_bf16(al[f], bh[j], acc[f][j], 0, 0, 0);
                __builtin_amdgcn_s_setprio(0);
#pragma unroll
                for (int f = 0; f < 4; ++f) al[f] = frag32(cbuf + 8192, wr * 128 + 64 + f * 16 + lr, lg);
                __builtin_amdgcn_s_setprio(1);
#pragma unroll
                for (int f = 0; f < 4; ++f)
#pragma unroll
                    for (int j = 0; j < 4; ++j)
                        acc[4 + f][j] = __builtin_amdgcn_mfma_f32_16x16x32_bf16(al[f], bh[j], acc[4 + f][j], 0, 0, 0);
                __builtin_amdgcn_s_setprio(0);
            }
            if (more) { VMW6(); } else { VMW0(); }
            BAR();

            // ---- segment 3: hi*lo ----
            if (more) stage_q32(Bl0, ldb, k1, nbuf + 24576, w, lane);
            {
                bf16x8 bl[4];
#pragma unroll
                for (int j = 0; j < 4; ++j) bl[j] = frag32(cbuf + 24576, wc * 64 + j * 16 + lr, lg);
                __builtin_amdgcn_s_setprio(1);
#pragma unroll
                for (int f = 0; f < 4; ++f)
#pragma unroll
                    for (int j = 0; j < 4; ++j)
                        acc[f][j] = __builtin_amdgcn_mfma_f32_16x16x32_bf16(ah0[f], bl[j], acc[f][j], 0, 0, 0);
#pragma unroll
                for (int f = 0; f < 4; ++f)
#pragma unroll
                    for (int j = 0; j < 4; ++j)
                        acc[4 + f][j] = __builtin_amdgcn_mfma_f32_16x16x32_bf16(ah1[f], bl[j], acc[4 + f][j], 0, 0, 0);
                __builtin_amdgcn_s_setprio(0);
            }
            if (more) { VMW4(); }
            BAR();
        }
    } else {
        // prologue: A_a(0), B(0), A_b(0)
        stage_h64(Ah0, lda, 0, smem + 0, w, lane, 0, 2);
        stage_full64(Bh0, ldb, 0, smem + 16384, w, lane);
        stage_h64(Ah0, lda, 0, smem + 0, w, lane, 1, 3);
        VMW2(); BAR();

        for (int t = 0; t < NT; ++t) {
            const unsigned short* cbuf = smem + (t & 1) * 32768;
            unsigned short* nbuf = smem + ((t + 1) & 1) * 32768;
            const int k1 = (t + 1) * KT;
            const bool more = (t + 1 < NT);
            const unsigned short* tA = cbuf;
            const unsigned short* tB = cbuf + 16384;

            // ---- segment 1: ih0 ----
            if (more) {
                stage_h64(Ah0, lda, k1, nbuf + 0, w, lane, 0, 2);
                stage_full64(Bh0, ldb, k1, nbuf + 16384, w, lane);
            }
            bf16x8 bfr[8];
#pragma unroll
            for (int j = 0; j < 4; ++j)
#pragma unroll
                for (int ks = 0; ks < 2; ++ks)
                    bfr[j * 2 + ks] = frag64(tB, wc * 64 + j * 16 + lr, ks * 4 + lg);
            {
                bf16x8 a0[8];
#pragma unroll
                for (int f = 0; f < 4; ++f)
#pragma unroll
                    for (int ks = 0; ks < 2; ++ks)
                        a0[f * 2 + ks] = frag64(tA, wr * 128 + f * 16 + lr, ks * 4 + lg);
                __builtin_amdgcn_s_setprio(1);
#pragma unroll
                for (int f = 0; f < 4; ++f)
#pragma unroll
                    for (int j = 0; j < 4; ++j) {
                        f32x4 a = acc[f][j];
                        a = __builtin_amdgcn_mfma_f32_16x16x32_bf16(a0[f * 2 + 0], bfr[j * 2 + 0], a, 0, 0, 0);
                        a = __builtin_amdgcn_mfma_f32_16x16x32_bf16(a0[f * 2 + 1], bfr[j * 2 + 1], a, 0, 0, 0);
                        acc[f][j] = a;
                    }
                __builtin_amdgcn_s_setprio(0);
            }
            if (more) { VMW6(); } else { VMW0(); }
            BAR();

            // ---- segment 2: ih1 ----
            if (more) stage_h64(Ah0, lda, k1, nbuf + 0, w, lane, 1, 3);
            {
                bf16x8 a1[8];
#pragma unroll
                for (int f = 0; f < 4; ++f)
#pragma unroll
                    for (int ks = 0; ks < 2; ++ks)
                        a1[f * 2 + ks] = frag64(tA, wr * 128 + 64 + f * 16 + lr, ks * 4 + lg);
                __builtin_amdgcn_s_setprio(1);
#pragma unroll
                for (int f = 0; f < 4; ++f)
#pragma unroll
                    for (int j = 0; j < 4; ++j) {
                        f32x4 a = acc[4 + f][j];
                        a = __builtin_amdgcn_mfma_f32_16x16x32_bf16(a1[f * 2 + 0], bfr[j * 2 + 0], a, 0, 0, 0);
                        a = __builtin_amdgcn_mfma_f32_16x16x32_bf16(a1[f * 2 + 1], bfr[j * 2 + 1], a, 0, 0, 0);
                        acc[4 + f][j] = a;
                    }
                __builtin_amdgcn_s_setprio(0);
            }
            if (more) { VMW2(); }
            BAR();
        }
    }

    // ---- epilogue: per-wave private LDS bounce (8KB each), no interior barriers ----
    __syncthreads();
    float* stg = reinterpret_cast<float*>(smem) + w * 2048;
    const int colg0 = colBase + wc * 64;
#pragma unroll
    for (int rnd = 0; rnd < 4; ++rnd) {
        const int rowg0 = rowBase + wr * 128 + rnd * 32;
#pragma unroll
        for (int ii = 0; ii < 2; ++ii)
#pragma unroll
            for (int j = 0; j < 4; ++j)
#pragma unroll
                for (int r2 = 0; r2 < 4; ++r2)
                    stg[(ii * 16 + lg * 4 + r2) * 64 + j * 16 + lr] = acc[rnd * 2 + ii][j][r2];

        if constexpr (OMODE == 0) {
#pragma unroll
            for (int t = 0; t < 8; ++t) {
                const int idx = t * 256 + lane * 4;
                const int r = idx >> 6, c = idx & 63;
                float4 v = *reinterpret_cast<const float4*>(&stg[idx]);
                const int colg = colg0 + c;
                if (mask != nullptr) {
                    const int4 mv = *reinterpret_cast<const int4*>(
                        &mask[(long long)b * strideMask + colg]);
                    v.x += NEG_INF_F * (float)mv.x;
                    v.y += NEG_INF_F * (float)mv.y;
                    v.z += NEG_INF_F * (float)mv.z;
                    v.w += NEG_INF_F * (float)mv.w;
                }
                *reinterpret_cast<float4*>(
                    &Cf[(long long)b * strideC + (long long)(rowg0 + r) * ldc + colg]) = v;
            }
        } else if constexpr (OMODE == 1) {
#pragma unroll
            for (int t = 0; t < 8; ++t) {
                const int idx = t * 256 + lane * 4;
                const int r = idx >> 6, c = idx & 63;
                const float4 v = *reinterpret_cast<const float4*>(&stg[idx]);
                ushort4 h, l;
                h.x = bf_rne(v.x); l.x = bf_rne(v.x - bf_to_f32(h.x));
                h.y = bf_rne(v.y); l.y = bf_rne(v.y - bf_to_f32(h.y));
                h.z = bf_rne(v.z); l.z = bf_rne(v.z - bf_to_f32(h.z));
                h.w = bf_rne(v.w); l.w = bf_rne(v.w - bf_to_f32(h.w));
                const long long cidx = (long long)(rowg0 + r) * ldc + colg0 + c;
                *reinterpret_cast<ushort4*>(&Ch[cidx]) = h;
                *reinterpret_cast<ushort4*>(&Cl[cidx]) = l;
            }
        } else {  // OMODE 3: V^T store  Ch[b2][col][s]
            const int b2 = rowg0 >> 11;
            const int s0 = rowg0 & 2047;
            const int colg = colg0 + lane;
            alignas(16) unsigned short u[32];
#pragma unroll
            for (int rr = 0; rr < 32; ++rr) u[rr] = bf_rne(stg[rr * 64 + lane]);
            unsigned short* vp = Ch + (long long)b2 * (1024LL * 2048)
                               + (long long)colg * 2048 + s0;
#pragma unroll
            for (int q = 0; q < 4; ++q)
                *reinterpret_cast<uint4*>(vp + q * 8) =
                    *reinterpret_cast<const uint4*>(&u[q * 8]);
        }
    }
}

// ---------------- helpers ----------------
__global__ __launch_bounds__(256) void split2_kernel(
    const float* __restrict__ in, unsigned short* __restrict__ hi,
    unsigned short* __restrict__ lo, long long n)
{
    for (long long i = ((long long)blockIdx.x * 256 + threadIdx.x) * 4; i < n;
         i += (long long)gridDim.x * 256 * 4) {
        float4 v = *reinterpret_cast<const float4*>(&in[i]);
        ushort4 h, l;
        h.x = bf_rne(v.x); l.x = bf_rne(v.x - bf_to_f32(h.x));
        h.y = bf_rne(v.y); l.y = bf_rne(v.y - bf_to_f32(h.y));
        h.z = bf_rne(v.z); l.z = bf_rne(v.z - bf_to_f32(h.z));
        h.w = bf_rne(v.w); l.w = bf_rne(v.w - bf_to_f32(h.w));
        *reinterpret_cast<ushort4*>(&hi[i]) = h;
        *reinterpret_cast<ushort4*>(&lo[i]) = l;
    }
}

__global__ __launch_bounds__(256) void cvt_kernel(
    const float* __restrict__ in, unsigned short* __restrict__ out, long long n)
{
    for (long long i = ((long long)blockIdx.x * 256 + threadIdx.x) * 4; i < n;
         i += (long long)gridDim.x * 256 * 4) {
        float4 v = *reinterpret_cast<const float4*>(&in[i]);
        ushort4 h;
        h.x = bf_rne(v.x); h.y = bf_rne(v.y); h.z = bf_rne(v.z); h.w = bf_rne(v.w);
        *reinterpret_cast<ushort4*>(&out[i]) = h;
    }
}

__global__ __launch_bounds__(256) void softmax_kernel(
    float* __restrict__ s, unsigned short* __restrict__ p)
{
    const long long row = blockIdx.x;
    float* sp = s + row * 2048;
    const int tid = threadIdx.x;

    float v[8];
    *reinterpret_cast<float4*>(&v[0]) = *reinterpret_cast<const float4*>(&sp[tid * 8]);
    *reinterpret_cast<float4*>(&v[4]) = *reinterpret_cast<const float4*>(&sp[tid * 8 + 4]);

    float m = v[0];
#pragma unroll
    for (int i = 1; i < 8; ++i) m = fmaxf(m, v[i]);
#pragma unroll
    for (int off = 1; off < 64; off <<= 1) m = fmaxf(m, __shfl_xor(m, off));

    __shared__ float redm[4];
    __shared__ float reds[4];
    if ((tid & 63) == 0) redm[tid >> 6] = m;
    __syncthreads();
    m = fmaxf(fmaxf(redm[0], redm[1]), fmaxf(redm[2], redm[3]));

    float sum = 0.f;
#pragma unroll
    for (int i = 0; i < 8; ++i) {
        v[i] = __expf(v[i] - m);
        sum += v[i];
    }
#pragma unroll
    for (int off = 1; off < 64; off <<= 1) sum += __shfl_xor(sum, off);
    if ((tid & 63) == 0) reds[tid >> 6] = sum;
    __syncthreads();
    sum = reds[0] + reds[1] + reds[2] + reds[3];

    const float inv = 1.0f / sum;
#pragma unroll
    for (int i = 0; i < 8; ++i) v[i] *= inv;

    *reinterpret_cast<float4*>(&sp[tid * 8])     = *reinterpret_cast<const float4*>(&v[0]);
    *reinterpret_cast<float4*>(&sp[tid * 8 + 4]) = *reinterpret_cast<const float4*>(&v[4]);

    ushort4 o0, o1;
    o0.x = bf_rne(v[0]); o0.y = bf_rne(v[1]); o0.z = bf_rne(v[2]); o0.w = bf_rne(v[3]);
    o1.x = bf_rne(v[4]); o1.y = bf_rne(v[5]); o1.z = bf_rne(v[6]); o1.w = bf_rne(v[7]);
    *reinterpret_cast<ushort4*>(&p[row * 2048 + tid * 8])     = o0;
    *reinterpret_cast<ushort4*>(&p[row * 2048 + tid * 8 + 4]) = o1;
}

extern "C" void kernel_launch(void* const* d_in, const int* in_sizes, int n_in,
                              void* d_out, int out_size, void* d_ws, size_t ws_size,
                              hipStream_t stream)
{
    (void)in_sizes; (void)n_in; (void)out_size; (void)ws_size;

    const int S = 2048, D = 1024;
    const long long BS  = 8LL * S;          // 16384
    const long long SD  = (long long)S * D;
    const long long SS  = (long long)S * S;
    const long long BSD = BS * D;
    const long long DD  = (long long)D * D;

    const float* x    = (const float*)d_in[0];
    const int*   mask = (const int*)d_in[1];
    const float* wq   = (const float*)d_in[2];
    const float* wk   = (const float*)d_in[3];
    const float* wv   = (const float*)d_in[4];

    float* out = (float*)d_out;             // [BS, D] f32 (final)
    float* s   = out + BSD;                 // [B, S, S] f32 (final)

    // ws: QKh [16384][2048] | QKl [16384][2048]  (bf16): Q = cols 0..1023, K = cols 1024..2047
    unsigned short* QKh = (unsigned short*)d_ws;
    unsigned short* QKl = QKh + BS * 2048;

    // x split lives in d_out's out-region until PV overwrites it
    unsigned short* xh = (unsigned short*)out;
    unsigned short* xl = xh + BSD;
    // stacked weight splits [wq;wk] live in d_out's s-region until scores overwrites it
    unsigned short* whh = (unsigned short*)s;      // [2048][1024] hi
    unsigned short* wll = whh + 2 * DD;            // [2048][1024] lo
    // after scores: p reuses QKh; V^T + wv-bf16 reuse QKl
    unsigned short* p   = QKh;                     // [B][S][S] bf16 (67MB)
    unsigned short* Vt  = QKl;                     // [B][D][S] bf16 (33.5MB)
    unsigned short* wvh = QKl + 8LL * 1024 * 2048; // [1024][1024] bf16

    dim3 blk256(256), blk512(512);

    split2_kernel<<<dim3(2048), blk256, 0, stream>>>(x, xh, xl, BSD);
    split2_kernel<<<dim3(512), blk256, 0, stream>>>(wq, whh, wll, DD);
    split2_kernel<<<dim3(512), blk256, 0, stream>>>(wk, whh + DD, wll + DD, DD);

    // Merged Q|K projection: M=16384, N=2048 (cols 0..1023 = Q, 1024..2047 = K)
    mfma_gemm256<3, 1><<<dim3(64, 8, 1), blk512, 0, stream>>>(
        xh, xl, 0, D, whh, wll, 0, D,
        nullptr, QKh, QKl, 0, 2048, D, nullptr, 0);

    // scores = Q @ K^T + NEG_INF*mask  (3-term, f32 out); Q,K are column slices
    mfma_gemm256<3, 0><<<dim3(8, 8, 8), blk512, 0, stream>>>(
        QKh, QKl, (long long)S * 2048, 2048,
        QKh + 1024, QKl + 1024, (long long)S * 2048, 2048,
        s, nullptr, nullptr, SS, S, D, mask, S);

    // softmax in place + bf16 p for PV (p overwrites QKh)
    softmax_kernel<<<dim3(16384), blk256, 0, stream>>>(s, p);

    // wv -> bf16, then V^T = (x @ wv^T)^T directly (1-term, transposed store)
    cvt_kernel<<<dim3(512), blk256, 0, stream>>>(wv, wvh, DD);
    mfma_gemm256<1, 3><<<dim3(64, 4, 1), blk512, 0, stream>>>(
        xh, nullptr, 0, D, wvh, nullptr, 0, D,
        nullptr, Vt, nullptr, 0, 0, D, nullptr, 0);

    // out = p @ V = p @ (V^T)^T  (1-term BK=64, NT form, f32 out)
    mfma_gemm256<1, 0><<<dim3(8, 4, 8), blk512, 0, stream>>>(
        p, nullptr, SS, S, Vt, nullptr, SD, S,
        out, nullptr, nullptr, SD, D, S, nullptr, 0);
}

// Round 8
// 493.927 us; speedup vs baseline: 1.0752x; 1.0752x over previous
//
#include <hip/hip_runtime.h>

#define NEG_INF_F (-1.0e9f)

typedef short bf16x8 __attribute__((ext_vector_type(8)));
typedef float f32x4 __attribute__((ext_vector_type(4)));

__device__ inline unsigned short bf_rne(float f) {
    unsigned u = __builtin_bit_cast(unsigned, f);
    u = (u + 0x7fffu + ((u >> 16) & 1u)) >> 16;
    return (unsigned short)u;
}
__device__ inline float bf_to_f32(unsigned short h) {
    unsigned u = ((unsigned)h) << 16;
    return __builtin_bit_cast(float, u);
}

// async global->LDS, 16B per lane; LDS dest = wave-uniform base + lane*16
__device__ inline void gload16(const unsigned short* g, unsigned short* l) {
    __builtin_amdgcn_global_load_lds(
        (const __attribute__((address_space(1))) unsigned int*)g,
        (__attribute__((address_space(3))) unsigned int*)l, 16, 0, 0);
}

// ---------------- 256x256 8-wave double-buffered GEMM (round-6 structure) ----
// C = A * B^T. TERMS: 3 = split hi/lo (Ah*Bh+Al*Bh+Ah*Bl), BK=32;
//              1 = hi only, BK=64.
// OMODE: 0 = f32 C (+ optional NEG_INF*mask[col]); 1 = split bf16 (Ch,Cl);
//        3 = bf16 transposed V^T store Ch[b2][col][s].

// TERMS=3 tile [256][32] bf16 (8192 ushorts), chunk swizzle ^((r>>1)&3)
__device__ inline bf16x8 frag32(const unsigned short* t, int r, int ch) {
    return *reinterpret_cast<const bf16x8*>(&t[r * 32 + (ch ^ ((r >> 1) & 3)) * 8]);
}
// TERMS=1 tile [256][64] bf16 (16384 ushorts), chunk swizzle ^(r&7)
__device__ inline bf16x8 frag64(const unsigned short* t, int r, int ch) {
    return *reinterpret_cast<const bf16x8*>(&t[r * 64 + (ch ^ (r & 7)) * 8]);
}

template <int TERMS>
__device__ inline void stage_ktile(
    const unsigned short* __restrict__ Ah0, const unsigned short* __restrict__ Al0, int lda,
    const unsigned short* __restrict__ Bh0, const unsigned short* __restrict__ Bl0, int ldb,
    int k0, unsigned short* buf, int w, int lane)
{
    if constexpr (TERMS == 3) {
#pragma unroll
        for (int c = 0; c < 2; ++c) {
            const int r = c * 128 + w * 16 + (lane >> 2);
            const int co = ((lane & 3) ^ ((r >> 1) & 3)) * 8;
            const int lb = (c * 128 + w * 16) * 32;
            gload16(Ah0 + (long long)r * lda + k0 + co, buf + lb);
            gload16(Al0 + (long long)r * lda + k0 + co, buf + 8192 + lb);
            gload16(Bh0 + (long long)r * ldb + k0 + co, buf + 16384 + lb);
            gload16(Bl0 + (long long)r * ldb + k0 + co, buf + 24576 + lb);
        }
    } else {
#pragma unroll
        for (int c = 0; c < 4; ++c) {
            const int r = c * 64 + w * 8 + (lane >> 3);
            const int co = ((lane & 7) ^ (r & 7)) * 8;
            const int lb = (c * 64 + w * 8) * 64;
            gload16(Ah0 + (long long)r * lda + k0 + co, buf + lb);
            gload16(Bh0 + (long long)r * ldb + k0 + co, buf + 16384 + lb);
        }
    }
}

template <int TERMS, int OMODE>
__global__ __launch_bounds__(512, 2) void mfma_gemm256(
    const unsigned short* __restrict__ Ah_g, const unsigned short* __restrict__ Al_g,
    long long strideA, int lda,
    const unsigned short* __restrict__ Bh_g, const unsigned short* __restrict__ Bl_g,
    long long strideB, int ldb,
    float* __restrict__ Cf, unsigned short* __restrict__ Ch, unsigned short* __restrict__ Cl,
    long long strideC, int ldc, int K,
    const int* __restrict__ mask, long long strideMask)
{
    constexpr int KT = (TERMS == 3) ? 32 : 64;
    const int b = blockIdx.z;
    const int tid = threadIdx.x;
    const int w = tid >> 6, lane = tid & 63;
    const int wr = w >> 2, wc = w & 3;
    const int lr = lane & 15, lg = lane >> 4;
    const int rowBase = blockIdx.x * 256;
    const int colBase = blockIdx.y * 256;

    __shared__ unsigned short smem[65536];  // 128 KB: 2 x 64KB buffers

    const unsigned short* Ah0 = Ah_g + (long long)b * strideA + (long long)rowBase * lda;
    const unsigned short* Bh0 = Bh_g + (long long)b * strideB + (long long)colBase * ldb;
    const unsigned short* Al0 = (TERMS == 3)
        ? Al_g + (long long)b * strideA + (long long)rowBase * lda : nullptr;
    const unsigned short* Bl0 = (TERMS == 3)
        ? Bl_g + (long long)b * strideB + (long long)colBase * ldb : nullptr;

    f32x4 acc[8][4] = {};
    const int NT = K / KT;

    stage_ktile<TERMS>(Ah0, Al0, lda, Bh0, Bl0, ldb, 0, smem, w, lane);
    __syncthreads();

    for (int kt = 0; kt < NT; ++kt) {
        unsigned short* cbuf = smem + (kt & 1) * 32768;
        if (kt + 1 < NT)
            stage_ktile<TERMS>(Ah0, Al0, lda, Bh0, Bl0, ldb, (kt + 1) * KT,
                               smem + ((kt + 1) & 1) * 32768, w, lane);

        if constexpr (TERMS == 3) {
            const unsigned short* tAh = cbuf;
            const unsigned short* tAl = cbuf + 8192;
            const unsigned short* tBh = cbuf + 16384;
            const unsigned short* tBl = cbuf + 24576;
            bf16x8 bh[4], bl[4];
#pragma unroll
            for (int j = 0; j < 4; ++j) {
                const int r = wc * 64 + j * 16 + lr;
                bh[j] = frag32(tBh, r, lg);
                bl[j] = frag32(tBl, r, lg);
            }
#pragma unroll
            for (int ih = 0; ih < 2; ++ih) {
                bf16x8 ah[4], al[4];
#pragma unroll
                for (int f = 0; f < 4; ++f) {
                    const int r = wr * 128 + ih * 64 + f * 16 + lr;
                    ah[f] = frag32(tAh, r, lg);
                    al[f] = frag32(tAl, r, lg);
                }
#pragma unroll
                for (int f = 0; f < 4; ++f)
#pragma unroll
                    for (int j = 0; j < 4; ++j) {
                        f32x4 a = acc[ih * 4 + f][j];
                        a = __builtin_amdgcn_mfma_f32_16x16x32_bf16(ah[f], bh[j], a, 0, 0, 0);
                        a = __builtin_amdgcn_mfma_f32_16x16x32_bf16(al[f], bh[j], a, 0, 0, 0);
                        a = __builtin_amdgcn_mfma_f32_16x16x32_bf16(ah[f], bl[j], a, 0, 0, 0);
                        acc[ih * 4 + f][j] = a;
                    }
            }
        } else {
            const unsigned short* tA = cbuf;
            const unsigned short* tB = cbuf + 16384;
            bf16x8 bh[8];
#pragma unroll
            for (int j = 0; j < 4; ++j)
#pragma unroll
                for (int ks = 0; ks < 2; ++ks)
                    bh[j * 2 + ks] = frag64(tB, wc * 64 + j * 16 + lr, ks * 4 + lg);
#pragma unroll
            for (int ih = 0; ih < 2; ++ih) {
                bf16x8 ah[8];
#pragma unroll
                for (int f = 0; f < 4; ++f)
#pragma unroll
                    for (int ks = 0; ks < 2; ++ks)
                        ah[f * 2 + ks] = frag64(tA, wr * 128 + ih * 64 + f * 16 + lr, ks * 4 + lg);
#pragma unroll
                for (int f = 0; f < 4; ++f)
#pragma unroll
                    for (int j = 0; j < 4; ++j) {
                        f32x4 a = acc[ih * 4 + f][j];
                        a = __builtin_amdgcn_mfma_f32_16x16x32_bf16(ah[f * 2 + 0], bh[j * 2 + 0], a, 0, 0, 0);
                        a = __builtin_amdgcn_mfma_f32_16x16x32_bf16(ah[f * 2 + 1], bh[j * 2 + 1], a, 0, 0, 0);
                        acc[ih * 4 + f][j] = a;
                    }
            }
        }
        __syncthreads();
    }

    // ---- epilogue: per-wave private LDS bounce (8KB each), no interior barriers ----
    __syncthreads();
    float* stg = reinterpret_cast<float*>(smem) + w * 2048;
    const int colg0 = colBase + wc * 64;
#pragma unroll
    for (int rnd = 0; rnd < 4; ++rnd) {
        const int rowg0 = rowBase + wr * 128 + rnd * 32;
#pragma unroll
        for (int ii = 0; ii < 2; ++ii)
#pragma unroll
            for (int j = 0; j < 4; ++j)
#pragma unroll
                for (int r2 = 0; r2 < 4; ++r2)
                    stg[(ii * 16 + lg * 4 + r2) * 64 + j * 16 + lr] = acc[rnd * 2 + ii][j][r2];

        if constexpr (OMODE == 0) {
#pragma unroll
            for (int t = 0; t < 8; ++t) {
                const int idx = t * 256 + lane * 4;
                const int r = idx >> 6, c = idx & 63;
                float4 v = *reinterpret_cast<const float4*>(&stg[idx]);
                const int colg = colg0 + c;
                if (mask != nullptr) {
                    const int4 mv = *reinterpret_cast<const int4*>(
                        &mask[(long long)b * strideMask + colg]);
                    v.x += NEG_INF_F * (float)mv.x;
                    v.y += NEG_INF_F * (float)mv.y;
                    v.z += NEG_INF_F * (float)mv.z;
                    v.w += NEG_INF_F * (float)mv.w;
                }
                *reinterpret_cast<float4*>(
                    &Cf[(long long)b * strideC + (long long)(rowg0 + r) * ldc + colg]) = v;
            }
        } else if constexpr (OMODE == 1) {
#pragma unroll
            for (int t = 0; t < 8; ++t) {
                const int idx = t * 256 + lane * 4;
                const int r = idx >> 6, c = idx & 63;
                const float4 v = *reinterpret_cast<const float4*>(&stg[idx]);
                ushort4 h, l;
                h.x = bf_rne(v.x); l.x = bf_rne(v.x - bf_to_f32(h.x));
                h.y = bf_rne(v.y); l.y = bf_rne(v.y - bf_to_f32(h.y));
                h.z = bf_rne(v.z); l.z = bf_rne(v.z - bf_to_f32(h.z));
                h.w = bf_rne(v.w); l.w = bf_rne(v.w - bf_to_f32(h.w));
                const long long cidx = (long long)(rowg0 + r) * ldc + colg0 + c;
                *reinterpret_cast<ushort4*>(&Ch[cidx]) = h;
                *reinterpret_cast<ushort4*>(&Cl[cidx]) = l;
            }
        } else {  // OMODE 3: V^T store  Ch[b2][col][s]
            const int b2 = rowg0 >> 11;
            const int s0 = rowg0 & 2047;
            const int colg = colg0 + lane;
            alignas(16) unsigned short u[32];
#pragma unroll
            for (int rr = 0; rr < 32; ++rr) u[rr] = bf_rne(stg[rr * 64 + lane]);
            unsigned short* vp = Ch + (long long)b2 * (1024LL * 2048)
                               + (long long)colg * 2048 + s0;
#pragma unroll
            for (int q = 0; q < 4; ++q)
                *reinterpret_cast<uint4*>(vp + q * 8) =
                    *reinterpret_cast<const uint4*>(&u[q * 8]);
        }
    }
}

// ---------------- helpers ----------------
__global__ __launch_bounds__(256) void split2_kernel(
    const float* __restrict__ in, unsigned short* __restrict__ hi,
    unsigned short* __restrict__ lo, long long n)
{
    for (long long i = ((long long)blockIdx.x * 256 + threadIdx.x) * 4; i < n;
         i += (long long)gridDim.x * 256 * 4) {
        float4 v = *reinterpret_cast<const float4*>(&in[i]);
        ushort4 h, l;
        h.x = bf_rne(v.x); l.x = bf_rne(v.x - bf_to_f32(h.x));
        h.y = bf_rne(v.y); l.y = bf_rne(v.y - bf_to_f32(h.y));
        h.z = bf_rne(v.z); l.z = bf_rne(v.z - bf_to_f32(h.z));
        h.w = bf_rne(v.w); l.w = bf_rne(v.w - bf_to_f32(h.w));
        *reinterpret_cast<ushort4*>(&hi[i]) = h;
        *reinterpret_cast<ushort4*>(&lo[i]) = l;
    }
}

// f32 [N][N] -> TRANSPOSED hi/lo bf16: hi[j][i] = split(in[i][j]).  N % 64 == 0.
__global__ __launch_bounds__(256) void tsplit_kernel(
    const float* __restrict__ in, unsigned short* __restrict__ hi,
    unsigned short* __restrict__ lo, int N)
{
    __shared__ float tile[64][65];
    const int bi = blockIdx.x * 64;   // input row base
    const int bj = blockIdx.y * 64;   // input col base
    const int t = threadIdx.x;
    const int c4 = (t & 15) * 4;
    const int r0 = (t >> 4) * 4;
#pragma unroll
    for (int rr = 0; rr < 4; ++rr) {
        float4 v = *reinterpret_cast<const float4*>(
            &in[(long long)(bi + r0 + rr) * N + bj + c4]);
        tile[r0 + rr][c4 + 0] = v.x;
        tile[r0 + rr][c4 + 1] = v.y;
        tile[r0 + rr][c4 + 2] = v.z;
        tile[r0 + rr][c4 + 3] = v.w;
    }
    __syncthreads();
    const int oc  = t >> 2;           // input col within tile
    const int or0 = (t & 3) * 16;     // input row offset
    alignas(16) unsigned short uh[16], ul[16];
#pragma unroll
    for (int e = 0; e < 16; ++e) {
        const float f = tile[or0 + e][oc];
        const unsigned short h = bf_rne(f);
        uh[e] = h;
        ul[e] = bf_rne(f - bf_to_f32(h));
    }
    unsigned short* hp = hi + (long long)(bj + oc) * N + bi + or0;
    unsigned short* lp = lo + (long long)(bj + oc) * N + bi + or0;
    *reinterpret_cast<uint4*>(hp)     = *reinterpret_cast<const uint4*>(&uh[0]);
    *reinterpret_cast<uint4*>(hp + 8) = *reinterpret_cast<const uint4*>(&uh[8]);
    *reinterpret_cast<uint4*>(lp)     = *reinterpret_cast<const uint4*>(&ul[0]);
    *reinterpret_cast<uint4*>(lp + 8) = *reinterpret_cast<const uint4*>(&ul[8]);
}

__global__ __launch_bounds__(256) void cvt_kernel(
    const float* __restrict__ in, unsigned short* __restrict__ out, long long n)
{
    for (long long i = ((long long)blockIdx.x * 256 + threadIdx.x) * 4; i < n;
         i += (long long)gridDim.x * 256 * 4) {
        float4 v = *reinterpret_cast<const float4*>(&in[i]);
        ushort4 h;
        h.x = bf_rne(v.x); h.y = bf_rne(v.y); h.z = bf_rne(v.z); h.w = bf_rne(v.w);
        *reinterpret_cast<ushort4*>(&out[i]) = h;
    }
}

__global__ __launch_bounds__(256) void softmax_kernel(
    float* __restrict__ s, unsigned short* __restrict__ p)
{
    const long long row = blockIdx.x;
    float* sp = s + row * 2048;
    const int tid = threadIdx.x;

    float v[8];
    *reinterpret_cast<float4*>(&v[0]) = *reinterpret_cast<const float4*>(&sp[tid * 8]);
    *reinterpret_cast<float4*>(&v[4]) = *reinterpret_cast<const float4*>(&sp[tid * 8 + 4]);

    float m = v[0];
#pragma unroll
    for (int i = 1; i < 8; ++i) m = fmaxf(m, v[i]);
#pragma unroll
    for (int off = 1; off < 64; off <<= 1) m = fmaxf(m, __shfl_xor(m, off));

    __shared__ float redm[4];
    __shared__ float reds[4];
    if ((tid & 63) == 0) redm[tid >> 6] = m;
    __syncthreads();
    m = fmaxf(fmaxf(redm[0], redm[1]), fmaxf(redm[2], redm[3]));

    float sum = 0.f;
#pragma unroll
    for (int i = 0; i < 8; ++i) {
        v[i] = __expf(v[i] - m);
        sum += v[i];
    }
#pragma unroll
    for (int off = 1; off < 64; off <<= 1) sum += __shfl_xor(sum, off);
    if ((tid & 63) == 0) reds[tid >> 6] = sum;
    __syncthreads();
    sum = reds[0] + reds[1] + reds[2] + reds[3];

    const float inv = 1.0f / sum;
#pragma unroll
    for (int i = 0; i < 8; ++i) v[i] *= inv;

    *reinterpret_cast<float4*>(&sp[tid * 8])     = *reinterpret_cast<const float4*>(&v[0]);
    *reinterpret_cast<float4*>(&sp[tid * 8 + 4]) = *reinterpret_cast<const float4*>(&v[4]);

    ushort4 o0, o1;
    o0.x = bf_rne(v[0]); o0.y = bf_rne(v[1]); o0.z = bf_rne(v[2]); o0.w = bf_rne(v[3]);
    o1.x = bf_rne(v[4]); o1.y = bf_rne(v[5]); o1.z = bf_rne(v[6]); o1.w = bf_rne(v[7]);
    *reinterpret_cast<ushort4*>(&p[row * 2048 + tid * 8])     = o0;
    *reinterpret_cast<ushort4*>(&p[row * 2048 + tid * 8 + 4]) = o1;
}

extern "C" void kernel_launch(void* const* d_in, const int* in_sizes, int n_in,
                              void* d_out, int out_size, void* d_ws, size_t ws_size,
                              hipStream_t stream)
{
    (void)in_sizes; (void)n_in; (void)out_size; (void)ws_size;

    const int S = 2048, D = 1024;
    const long long BS  = 8LL * S;          // 16384
    const long long SD  = (long long)S * D;
    const long long SS  = (long long)S * S;
    const long long BSD = BS * D;
    const long long DD  = (long long)D * D;

    const float* x    = (const float*)d_in[0];
    const int*   mask = (const int*)d_in[1];
    const float* wq   = (const float*)d_in[2];
    const float* wk   = (const float*)d_in[3];
    const float* wv   = (const float*)d_in[4];

    float* out = (float*)d_out;             // [BS, D] f32 (final)
    float* s   = out + BSD;                 // [B, S, S] f32 (final)

    // ws layout (ushorts):
    //   Gh [16384][1024] | Gl [16384][1024]   (later overwritten by p [B][S][S])
    //   Vt [B][D][S] | wvh [1024][1024] | Mth | Mtl
    unsigned short* Gh  = (unsigned short*)d_ws;
    unsigned short* Gl  = Gh + BSD;
    unsigned short* p   = Gh;               // 2*BSD ushorts, overwrites Gh+Gl
    unsigned short* Vt  = Gh + 2 * BSD;
    unsigned short* wvh = Gh + 3 * BSD;
    unsigned short* Mth = wvh + DD;
    unsigned short* Mtl = Mth + DD;

    // x split lives in d_out's out-region until PV overwrites it
    unsigned short* xh = (unsigned short*)out;
    unsigned short* xl = xh + BSD;
    // transposed weight splits live in d_out's s-region until scores overwrites it
    unsigned short* wqTh = (unsigned short*)s;   // [1024][1024] = wq^T hi
    unsigned short* wqTl = wqTh + DD;
    unsigned short* wkTh = wqTl + DD;
    unsigned short* wkTl = wkTh + DD;

    dim3 blk256(256), blk512(512);

    split2_kernel<<<dim3(2048), blk256, 0, stream>>>(x, xh, xl, BSD);
    tsplit_kernel<<<dim3(16, 16), blk256, 0, stream>>>(wq, wqTh, wqTl, D);
    tsplit_kernel<<<dim3(16, 16), blk256, 0, stream>>>(wk, wkTh, wkTl, D);

    // Mt[j][i] = sum_e wk[e][j]*wq[e][i]  (= M^T where M = wq^T wk)
    // NT gemm: A = wkT, B = wqT, 3-term, split output
    mfma_gemm256<3, 1><<<dim3(4, 4, 1), blk512, 0, stream>>>(
        wkTh, wkTl, 0, D, wqTh, wqTl, 0, D,
        nullptr, Mth, Mtl, 0, D, D, nullptr, 0);

    // G = x @ Mt^T = x @ M  ([16384][1024], 3-term, split output)
    mfma_gemm256<3, 1><<<dim3(64, 4, 1), blk512, 0, stream>>>(
        xh, xl, 0, D, Mth, Mtl, 0, D,
        nullptr, Gh, Gl, 0, D, D, nullptr, 0);

    // scores = G @ x^T + NEG_INF*mask  (3-term, f32 out)
    mfma_gemm256<3, 0><<<dim3(8, 8, 8), blk512, 0, stream>>>(
        Gh, Gl, SD, D, xh, xl, SD, D,
        s, nullptr, nullptr, SS, S, D, mask, S);

    // softmax in place + bf16 p for PV (p overwrites Gh/Gl)
    softmax_kernel<<<dim3(16384), blk256, 0, stream>>>(s, p);

    // wv -> bf16, then V^T = (x @ wv^T)^T directly (1-term, transposed store)
    cvt_kernel<<<dim3(512), blk256, 0, stream>>>(wv, wvh, DD);
    mfma_gemm256<1, 3><<<dim3(64, 4, 1), blk512, 0, stream>>>(
        xh, nullptr, 0, D, wvh, nullptr, 0, D,
        nullptr, Vt, nullptr, 0, 0, D, nullptr, 0);

    // out = p @ V = p @ (V^T)^T  (1-term BK=64, NT form, f32 out)
    mfma_gemm256<1, 0><<<dim3(8, 4, 8), blk512, 0, stream>>>(
        p, nullptr, SS, S, Vt, nullptr, SD, S,
        out, nullptr, nullptr, SD, D, S, nullptr, 0);
}

// Round 9
// 420.995 us; speedup vs baseline: 1.2614x; 1.1732x over previous
//
#include <hip/hip_runtime.h>

#define NEG_INF_F (-1.0e9f)

typedef _Float16 f16x8 __attribute__((ext_vector_type(8)));
typedef float f32x4 __attribute__((ext_vector_type(4)));

__device__ inline unsigned short f16_of(float f) {
    _Float16 h = (_Float16)f;
    return __builtin_bit_cast(unsigned short, h);
}
__device__ inline float f32_of(unsigned short u) {
    return (float)__builtin_bit_cast(_Float16, u);
}

// async global->LDS, 16B per lane; LDS dest = wave-uniform base + lane*16
__device__ inline void gload16(const unsigned short* g, unsigned short* l) {
    __builtin_amdgcn_global_load_lds(
        (const __attribute__((address_space(1))) unsigned int*)g,
        (__attribute__((address_space(3))) unsigned int*)l, 16, 0, 0);
}

// ---------------- 256x256 8-wave double-buffered GEMM (f16, round-6 loop) ----
// C = A * B^T. TERMS: 2 = A split (Ah*B + Al*B), B single, BK=32;
//              1 = single A,B, BK=64.
// OMODE: 0 = f32 C (+ optional NEG_INF*mask[col]); 1 = split f16 (Ch,Cl);
//        2 = plain f16 (Ch); 3 = f16 transposed V^T store Ch[b2][col][s].

// [256][32]-f16 tile, chunk swizzle ^((r>>1)&3)
__device__ inline f16x8 frag32(const unsigned short* t, int r, int ch) {
    return *reinterpret_cast<const f16x8*>(&t[r * 32 + (ch ^ ((r >> 1) & 3)) * 8]);
}
// [256][64]-f16 tile, chunk swizzle ^(r&7)
__device__ inline f16x8 frag64(const unsigned short* t, int r, int ch) {
    return *reinterpret_cast<const f16x8*>(&t[r * 64 + (ch ^ (r & 7)) * 8]);
}

template <int TERMS>
__device__ inline void stage_ktile(
    const unsigned short* __restrict__ Ah0, const unsigned short* __restrict__ Al0, int lda,
    const unsigned short* __restrict__ Bh0, int ldb,
    int k0, unsigned short* buf, int w, int lane)
{
    if constexpr (TERMS == 2) {
        // Ah@0, Al@8192, B@16384 (halves). 6 gloads/wave.
#pragma unroll
        for (int c = 0; c < 2; ++c) {
            const int r = c * 128 + w * 16 + (lane >> 2);
            const int co = ((lane & 3) ^ ((r >> 1) & 3)) * 8;
            const int lb = (c * 128 + w * 16) * 32;
            gload16(Ah0 + (long long)r * lda + k0 + co, buf + lb);
            gload16(Al0 + (long long)r * lda + k0 + co, buf + 8192 + lb);
            gload16(Bh0 + (long long)r * ldb + k0 + co, buf + 16384 + lb);
        }
    } else {
        // A@0, B@16384 (halves). 6 gloads/wave.
#pragma unroll
        for (int c = 0; c < 4; ++c) {
            const int r = c * 64 + w * 8 + (lane >> 3);
            const int co = ((lane & 7) ^ (r & 7)) * 8;
            const int lb = (c * 64 + w * 8) * 64;
            gload16(Ah0 + (long long)r * lda + k0 + co, buf + lb);
            gload16(Bh0 + (long long)r * ldb + k0 + co, buf + 16384 + lb);
        }
    }
}

template <int TERMS, int OMODE>
__global__ __launch_bounds__(512, 2) void mfma_gemm256(
    const unsigned short* __restrict__ Ah_g, const unsigned short* __restrict__ Al_g,
    long long strideA, int lda,
    const unsigned short* __restrict__ Bh_g,
    long long strideB, int ldb,
    float* __restrict__ Cf, unsigned short* __restrict__ Ch, unsigned short* __restrict__ Cl,
    long long strideC, int ldc, int K,
    const int* __restrict__ mask, long long strideMask)
{
    constexpr int KT  = (TERMS == 2) ? 32 : 64;
    constexpr int BUF = (TERMS == 2) ? 24576 : 32768;  // halves per buffer
    const int b = blockIdx.z;
    const int tid = threadIdx.x;
    const int w = tid >> 6, lane = tid & 63;
    const int wr = w >> 2, wc = w & 3;
    const int lr = lane & 15, lg = lane >> 4;
    const int rowBase = blockIdx.x * 256;
    const int colBase = blockIdx.y * 256;

    __shared__ unsigned short smem[(TERMS == 2) ? 49152 : 65536];

    const unsigned short* Ah0 = Ah_g + (long long)b * strideA + (long long)rowBase * lda;
    const unsigned short* Bh0 = Bh_g + (long long)b * strideB + (long long)colBase * ldb;
    const unsigned short* Al0 = (TERMS == 2)
        ? Al_g + (long long)b * strideA + (long long)rowBase * lda : nullptr;

    f32x4 acc[8][4] = {};
    const int NT = K / KT;

    stage_ktile<TERMS>(Ah0, Al0, lda, Bh0, ldb, 0, smem, w, lane);
    __syncthreads();

    for (int kt = 0; kt < NT; ++kt) {
        unsigned short* cbuf = smem + (kt & 1) * BUF;
        if (kt + 1 < NT)
            stage_ktile<TERMS>(Ah0, Al0, lda, Bh0, ldb, (kt + 1) * KT,
                               smem + ((kt + 1) & 1) * BUF, w, lane);

        if constexpr (TERMS == 2) {
            const unsigned short* tAh = cbuf;
            const unsigned short* tAl = cbuf + 8192;
            const unsigned short* tB  = cbuf + 16384;
            f16x8 bh[4];
#pragma unroll
            for (int j = 0; j < 4; ++j)
                bh[j] = frag32(tB, wc * 64 + j * 16 + lr, lg);
#pragma unroll
            for (int ih = 0; ih < 2; ++ih) {
                f16x8 ah[4], al[4];
#pragma unroll
                for (int f = 0; f < 4; ++f) {
                    const int r = wr * 128 + ih * 64 + f * 16 + lr;
                    ah[f] = frag32(tAh, r, lg);
                    al[f] = frag32(tAl, r, lg);
                }
#pragma unroll
                for (int f = 0; f < 4; ++f)
#pragma unroll
                    for (int j = 0; j < 4; ++j) {
                        f32x4 a = acc[ih * 4 + f][j];
                        a = __builtin_amdgcn_mfma_f32_16x16x32_f16(ah[f], bh[j], a, 0, 0, 0);
                        a = __builtin_amdgcn_mfma_f32_16x16x32_f16(al[f], bh[j], a, 0, 0, 0);
                        acc[ih * 4 + f][j] = a;
                    }
            }
        } else {
            const unsigned short* tA = cbuf;
            const unsigned short* tB = cbuf + 16384;
            f16x8 bh[8];
#pragma unroll
            for (int j = 0; j < 4; ++j)
#pragma unroll
                for (int ks = 0; ks < 2; ++ks)
                    bh[j * 2 + ks] = frag64(tB, wc * 64 + j * 16 + lr, ks * 4 + lg);
#pragma unroll
            for (int ih = 0; ih < 2; ++ih) {
                f16x8 ah[8];
#pragma unroll
                for (int f = 0; f < 4; ++f)
#pragma unroll
                    for (int ks = 0; ks < 2; ++ks)
                        ah[f * 2 + ks] = frag64(tA, wr * 128 + ih * 64 + f * 16 + lr, ks * 4 + lg);
#pragma unroll
                for (int f = 0; f < 4; ++f)
#pragma unroll
                    for (int j = 0; j < 4; ++j) {
                        f32x4 a = acc[ih * 4 + f][j];
                        a = __builtin_amdgcn_mfma_f32_16x16x32_f16(ah[f * 2 + 0], bh[j * 2 + 0], a, 0, 0, 0);
                        a = __builtin_amdgcn_mfma_f32_16x16x32_f16(ah[f * 2 + 1], bh[j * 2 + 1], a, 0, 0, 0);
                        acc[ih * 4 + f][j] = a;
                    }
            }
        }
        __syncthreads();
    }

    // ---- epilogue: per-wave private LDS bounce (8KB each), no interior barriers ----
    __syncthreads();
    float* stg = reinterpret_cast<float*>(smem) + w * 2048;
    const int colg0 = colBase + wc * 64;
#pragma unroll
    for (int rnd = 0; rnd < 4; ++rnd) {
        const int rowg0 = rowBase + wr * 128 + rnd * 32;
#pragma unroll
        for (int ii = 0; ii < 2; ++ii)
#pragma unroll
            for (int j = 0; j < 4; ++j)
#pragma unroll
                for (int r2 = 0; r2 < 4; ++r2)
                    stg[(ii * 16 + lg * 4 + r2) * 64 + j * 16 + lr] = acc[rnd * 2 + ii][j][r2];

        if constexpr (OMODE == 0) {
#pragma unroll
            for (int t = 0; t < 8; ++t) {
                const int idx = t * 256 + lane * 4;
                const int r = idx >> 6, c = idx & 63;
                float4 v = *reinterpret_cast<const float4*>(&stg[idx]);
                const int colg = colg0 + c;
                if (mask != nullptr) {
                    const int4 mv = *reinterpret_cast<const int4*>(
                        &mask[(long long)b * strideMask + colg]);
                    v.x += NEG_INF_F * (float)mv.x;
                    v.y += NEG_INF_F * (float)mv.y;
                    v.z += NEG_INF_F * (float)mv.z;
                    v.w += NEG_INF_F * (float)mv.w;
                }
                *reinterpret_cast<float4*>(
                    &Cf[(long long)b * strideC + (long long)(rowg0 + r) * ldc + colg]) = v;
            }
        } else if constexpr (OMODE == 1) {
#pragma unroll
            for (int t = 0; t < 8; ++t) {
                const int idx = t * 256 + lane * 4;
                const int r = idx >> 6, c = idx & 63;
                const float4 v = *reinterpret_cast<const float4*>(&stg[idx]);
                ushort4 h, l;
                h.x = f16_of(v.x); l.x = f16_of(v.x - f32_of(h.x));
                h.y = f16_of(v.y); l.y = f16_of(v.y - f32_of(h.y));
                h.z = f16_of(v.z); l.z = f16_of(v.z - f32_of(h.z));
                h.w = f16_of(v.w); l.w = f16_of(v.w - f32_of(h.w));
                const long long cidx = (long long)(rowg0 + r) * ldc + colg0 + c;
                *reinterpret_cast<ushort4*>(&Ch[cidx]) = h;
                *reinterpret_cast<ushort4*>(&Cl[cidx]) = l;
            }
        } else if constexpr (OMODE == 2) {
#pragma unroll
            for (int t = 0; t < 8; ++t) {
                const int idx = t * 256 + lane * 4;
                const int r = idx >> 6, c = idx & 63;
                const float4 v = *reinterpret_cast<const float4*>(&stg[idx]);
                ushort4 h;
                h.x = f16_of(v.x); h.y = f16_of(v.y);
                h.z = f16_of(v.z); h.w = f16_of(v.w);
                *reinterpret_cast<ushort4*>(
                    &Ch[(long long)(rowg0 + r) * ldc + colg0 + c]) = h;
            }
        } else {  // OMODE 3: V^T store  Ch[b2][col][s]
            const int b2 = rowg0 >> 11;
            const int s0 = rowg0 & 2047;
            const int colg = colg0 + lane;
            alignas(16) unsigned short u[32];
#pragma unroll
            for (int rr = 0; rr < 32; ++rr) u[rr] = f16_of(stg[rr * 64 + lane]);
            unsigned short* vp = Ch + (long long)b2 * (1024LL * 2048)
                               + (long long)colg * 2048 + s0;
#pragma unroll
            for (int q = 0; q < 4; ++q)
                *reinterpret_cast<uint4*>(vp + q * 8) =
                    *reinterpret_cast<const uint4*>(&u[q * 8]);
        }
    }
}

// ---------------- helpers ----------------
// f32 -> (hi, lo) f16 split
__global__ __launch_bounds__(256) void split2_kernel(
    const float* __restrict__ in, unsigned short* __restrict__ hi,
    unsigned short* __restrict__ lo, long long n)
{
    for (long long i = ((long long)blockIdx.x * 256 + threadIdx.x) * 4; i < n;
         i += (long long)gridDim.x * 256 * 4) {
        float4 v = *reinterpret_cast<const float4*>(&in[i]);
        ushort4 h, l;
        h.x = f16_of(v.x); l.x = f16_of(v.x - f32_of(h.x));
        h.y = f16_of(v.y); l.y = f16_of(v.y - f32_of(h.y));
        h.z = f16_of(v.z); l.z = f16_of(v.z - f32_of(h.z));
        h.w = f16_of(v.w); l.w = f16_of(v.w - f32_of(h.w));
        *reinterpret_cast<ushort4*>(&hi[i]) = h;
        *reinterpret_cast<ushort4*>(&lo[i]) = l;
    }
}

// f32 [N][N] -> TRANSPOSED hi/lo f16: hi[j][i] = split(in[i][j]).  N % 64 == 0.
__global__ __launch_bounds__(256) void tsplit_kernel(
    const float* __restrict__ in, unsigned short* __restrict__ hi,
    unsigned short* __restrict__ lo, int N)
{
    __shared__ float tile[64][65];
    const int bi = blockIdx.x * 64;
    const int bj = blockIdx.y * 64;
    const int t = threadIdx.x;
    const int c4 = (t & 15) * 4;
    const int r0 = (t >> 4) * 4;
#pragma unroll
    for (int rr = 0; rr < 4; ++rr) {
        float4 v = *reinterpret_cast<const float4*>(
            &in[(long long)(bi + r0 + rr) * N + bj + c4]);
        tile[r0 + rr][c4 + 0] = v.x;
        tile[r0 + rr][c4 + 1] = v.y;
        tile[r0 + rr][c4 + 2] = v.z;
        tile[r0 + rr][c4 + 3] = v.w;
    }
    __syncthreads();
    const int oc  = t >> 2;
    const int or0 = (t & 3) * 16;
    alignas(16) unsigned short uh[16], ul[16];
#pragma unroll
    for (int e = 0; e < 16; ++e) {
        const float f = tile[or0 + e][oc];
        const unsigned short h = f16_of(f);
        uh[e] = h;
        ul[e] = f16_of(f - f32_of(h));
    }
    unsigned short* hp = hi + (long long)(bj + oc) * N + bi + or0;
    unsigned short* lp = lo + (long long)(bj + oc) * N + bi + or0;
    *reinterpret_cast<uint4*>(hp)     = *reinterpret_cast<const uint4*>(&uh[0]);
    *reinterpret_cast<uint4*>(hp + 8) = *reinterpret_cast<const uint4*>(&uh[8]);
    *reinterpret_cast<uint4*>(lp)     = *reinterpret_cast<const uint4*>(&ul[0]);
    *reinterpret_cast<uint4*>(lp + 8) = *reinterpret_cast<const uint4*>(&ul[8]);
}

// f32 -> f16
__global__ __launch_bounds__(256) void cvt_kernel(
    const float* __restrict__ in, unsigned short* __restrict__ out, long long n)
{
    for (long long i = ((long long)blockIdx.x * 256 + threadIdx.x) * 4; i < n;
         i += (long long)gridDim.x * 256 * 4) {
        float4 v = *reinterpret_cast<const float4*>(&in[i]);
        ushort4 h;
        h.x = f16_of(v.x); h.y = f16_of(v.y); h.z = f16_of(v.z); h.w = f16_of(v.w);
        *reinterpret_cast<ushort4*>(&out[i]) = h;
    }
}

// In-place f32 row softmax (rows=16384, cols=2048) + f16 copy for PV.
__global__ __launch_bounds__(256) void softmax_kernel(
    float* __restrict__ s, unsigned short* __restrict__ p)
{
    const long long row = blockIdx.x;
    float* sp = s + row * 2048;
    const int tid = threadIdx.x;

    float v[8];
    *reinterpret_cast<float4*>(&v[0]) = *reinterpret_cast<const float4*>(&sp[tid * 8]);
    *reinterpret_cast<float4*>(&v[4]) = *reinterpret_cast<const float4*>(&sp[tid * 8 + 4]);

    float m = v[0];
#pragma unroll
    for (int i = 1; i < 8; ++i) m = fmaxf(m, v[i]);
#pragma unroll
    for (int off = 1; off < 64; off <<= 1) m = fmaxf(m, __shfl_xor(m, off));

    __shared__ float redm[4];
    __shared__ float reds[4];
    if ((tid & 63) == 0) redm[tid >> 6] = m;
    __syncthreads();
    m = fmaxf(fmaxf(redm[0], redm[1]), fmaxf(redm[2], redm[3]));

    float sum = 0.f;
#pragma unroll
    for (int i = 0; i < 8; ++i) {
        v[i] = __expf(v[i] - m);
        sum += v[i];
    }
#pragma unroll
    for (int off = 1; off < 64; off <<= 1) sum += __shfl_xor(sum, off);
    if ((tid & 63) == 0) reds[tid >> 6] = sum;
    __syncthreads();
    sum = reds[0] + reds[1] + reds[2] + reds[3];

    const float inv = 1.0f / sum;
#pragma unroll
    for (int i = 0; i < 8; ++i) v[i] *= inv;

    *reinterpret_cast<float4*>(&sp[tid * 8])     = *reinterpret_cast<const float4*>(&v[0]);
    *reinterpret_cast<float4*>(&sp[tid * 8 + 4]) = *reinterpret_cast<const float4*>(&v[4]);

    ushort4 o0, o1;
    o0.x = f16_of(v[0]); o0.y = f16_of(v[1]); o0.z = f16_of(v[2]); o0.w = f16_of(v[3]);
    o1.x = f16_of(v[4]); o1.y = f16_of(v[5]); o1.z = f16_of(v[6]); o1.w = f16_of(v[7]);
    *reinterpret_cast<ushort4*>(&p[row * 2048 + tid * 8])     = o0;
    *reinterpret_cast<ushort4*>(&p[row * 2048 + tid * 8 + 4]) = o1;
}

extern "C" void kernel_launch(void* const* d_in, const int* in_sizes, int n_in,
                              void* d_out, int out_size, void* d_ws, size_t ws_size,
                              hipStream_t stream)
{
    (void)in_sizes; (void)n_in; (void)out_size; (void)ws_size;

    const int S = 2048, D = 1024;
    const long long BS  = 8LL * S;          // 16384
    const long long SD  = (long long)S * D;
    const long long SS  = (long long)S * S;
    const long long BSD = BS * D;
    const long long DD  = (long long)D * D;

    const float* x    = (const float*)d_in[0];
    const int*   mask = (const int*)d_in[1];
    const float* wq   = (const float*)d_in[2];
    const float* wk   = (const float*)d_in[3];
    const float* wv   = (const float*)d_in[4];

    float* out = (float*)d_out;             // [BS, D] f32 (final)
    float* s   = out + BSD;                 // [B, S, S] f32 (final)

    // ws layout (halves):
    //   Gh [16384][1024] | Gl [16384][1024]   (later overwritten by p [B][S][S])
    //   Vt [B][D][S] | wvh | Mth
    unsigned short* Gh  = (unsigned short*)d_ws;
    unsigned short* Gl  = Gh + BSD;
    unsigned short* p   = Gh;               // 2*BSD halves, overwrites Gh+Gl
    unsigned short* Vt  = Gh + 2 * BSD;
    unsigned short* wvh = Gh + 3 * BSD;
    unsigned short* Mth = wvh + DD;

    // x split lives in d_out's out-region until PV overwrites it
    unsigned short* xh = (unsigned short*)out;
    unsigned short* xl = xh + BSD;
    // transposed weight splits live in d_out's s-region until scores overwrites it
    unsigned short* wqTh = (unsigned short*)s;   // [1024][1024] = wq^T hi
    unsigned short* wqTl = wqTh + DD;
    unsigned short* wkTh = wqTl + DD;
    unsigned short* wkTl = wkTh + DD;

    dim3 blk256(256), blk512(512);

    split2_kernel<<<dim3(2048), blk256, 0, stream>>>(x, xh, xl, BSD);
    tsplit_kernel<<<dim3(16, 16), blk256, 0, stream>>>(wq, wqTh, wqTl, D);
    tsplit_kernel<<<dim3(16, 16), blk256, 0, stream>>>(wk, wkTh, wkTl, D);

    // Mt[j][i] = sum_e wk[e][j]*wq[e][i]; A = (wkTh,wkTl) split, B = wqTh, plain f16 out
    mfma_gemm256<2, 2><<<dim3(4, 4, 1), blk512, 0, stream>>>(
        wkTh, wkTl, 0, D, wqTh, 0, D,
        nullptr, Mth, nullptr, 0, D, D, nullptr, 0);

    // G = x @ Mt^T: A = (xh,xl) split, B = Mth; split-f16 out (Gh,Gl)
    mfma_gemm256<2, 1><<<dim3(64, 4, 1), blk512, 0, stream>>>(
        xh, xl, 0, D, Mth, 0, D,
        nullptr, Gh, Gl, 0, D, D, nullptr, 0);

    // scores = G @ x^T + NEG_INF*mask: A = (Gh,Gl) split, B = xh; f32 out
    mfma_gemm256<2, 0><<<dim3(8, 8, 8), blk512, 0, stream>>>(
        Gh, Gl, SD, D, xh, SD, D,
        s, nullptr, nullptr, SS, S, D, mask, S);

    // softmax in place + f16 p for PV (p overwrites Gh/Gl)
    softmax_kernel<<<dim3(16384), blk256, 0, stream>>>(s, p);

    // wv -> f16, then V^T = (x @ wv^T)^T directly (1-term, transposed store)
    cvt_kernel<<<dim3(512), blk256, 0, stream>>>(wv, wvh, DD);
    mfma_gemm256<1, 3><<<dim3(64, 4, 1), blk512, 0, stream>>>(
        xh, nullptr, 0, D, wvh, 0, D,
        nullptr, Vt, nullptr, 0, 0, D, nullptr, 0);

    // out = p @ V = p @ (V^T)^T  (1-term BK=64, NT form, f32 out)
    mfma_gemm256<1, 0><<<dim3(8, 4, 8), blk512, 0, stream>>>(
        p, nullptr, SS, S, Vt, SD, S,
        out, nullptr, nullptr, SD, D, S, nullptr, 0);
}

// Round 10
// 419.301 us; speedup vs baseline: 1.2665x; 1.0040x over previous
//
#include <hip/hip_runtime.h>

#define NEG_INF_F (-1.0e9f)

typedef _Float16 f16x8 __attribute__((ext_vector_type(8)));
typedef float f32x4 __attribute__((ext_vector_type(4)));

__device__ inline unsigned short f16_of(float f) {
    _Float16 h = (_Float16)f;
    return __builtin_bit_cast(unsigned short, h);
}
__device__ inline float f32_of(unsigned short u) {
    return (float)__builtin_bit_cast(_Float16, u);
}

// async global->LDS, 16B per lane; LDS dest = wave-uniform base + lane*16
__device__ inline void gload16(const unsigned short* g, unsigned short* l) {
    __builtin_amdgcn_global_load_lds(
        (const __attribute__((address_space(1))) unsigned int*)g,
        (__attribute__((address_space(3))) unsigned int*)l, 16, 0, 0);
}

// ---------------- 256x256 8-wave double-buffered GEMM (f16) ----------------
// C = A * B^T. TERMS: 2 = A split (Ah*B + Al*B), B single, BK=32,
//                     waves 4row x 2col (wave tile 64x128) -- A-read redundancy 2;
//              1 = single A,B, BK=64, waves 2row x 4col (wave tile 128x64).
// OMODE: 0 = f32 C (+ optional NEG_INF*mask[col]); 1 = split f16 (Ch,Cl);
//        2 = plain f16 (Ch); 3 = f16 transposed V^T store Ch[b2][col][s].

// [256][32]-f16 tile, chunk swizzle ^((r>>1)&3)
__device__ inline f16x8 frag32(const unsigned short* t, int r, int ch) {
    return *reinterpret_cast<const f16x8*>(&t[r * 32 + (ch ^ ((r >> 1) & 3)) * 8]);
}
// [256][64]-f16 tile, chunk swizzle ^(r&7)
__device__ inline f16x8 frag64(const unsigned short* t, int r, int ch) {
    return *reinterpret_cast<const f16x8*>(&t[r * 64 + (ch ^ (r & 7)) * 8]);
}

template <int TERMS>
__device__ inline void stage_ktile(
    const unsigned short* __restrict__ Ah0, const unsigned short* __restrict__ Al0, int lda,
    const unsigned short* __restrict__ Bh0, int ldb,
    int k0, unsigned short* buf, int w, int lane)
{
    if constexpr (TERMS == 2) {
        // Ah@0, Al@8192, B@16384 (halves). 6 gloads/wave.
#pragma unroll
        for (int c = 0; c < 2; ++c) {
            const int r = c * 128 + w * 16 + (lane >> 2);
            const int co = ((lane & 3) ^ ((r >> 1) & 3)) * 8;
            const int lb = (c * 128 + w * 16) * 32;
            gload16(Ah0 + (long long)r * lda + k0 + co, buf + lb);
            gload16(Al0 + (long long)r * lda + k0 + co, buf + 8192 + lb);
            gload16(Bh0 + (long long)r * ldb + k0 + co, buf + 16384 + lb);
        }
    } else {
        // A@0, B@16384 (halves). 6 gloads/wave.
#pragma unroll
        for (int c = 0; c < 4; ++c) {
            const int r = c * 64 + w * 8 + (lane >> 3);
            const int co = ((lane & 7) ^ (r & 7)) * 8;
            const int lb = (c * 64 + w * 8) * 64;
            gload16(Ah0 + (long long)r * lda + k0 + co, buf + lb);
            gload16(Bh0 + (long long)r * ldb + k0 + co, buf + 16384 + lb);
        }
    }
}

template <int TERMS, int OMODE>
__global__ __launch_bounds__(512, 2) void mfma_gemm256(
    const unsigned short* __restrict__ Ah_g, const unsigned short* __restrict__ Al_g,
    long long strideA, int lda,
    const unsigned short* __restrict__ Bh_g,
    long long strideB, int ldb,
    float* __restrict__ Cf, unsigned short* __restrict__ Ch, unsigned short* __restrict__ Cl,
    long long strideC, int ldc, int K,
    const int* __restrict__ mask, long long strideMask)
{
    constexpr int KT  = (TERMS == 2) ? 32 : 64;
    constexpr int BUF = (TERMS == 2) ? 24576 : 32768;  // halves per buffer
    const int b = blockIdx.z;
    const int tid = threadIdx.x;
    const int w = tid >> 6, lane = tid & 63;
    const int lr = lane & 15, lg = lane >> 4;
    const int rowBase = blockIdx.x * 256;
    const int colBase = blockIdx.y * 256;

    // wave grids: TERMS=2 -> 4 row-groups x 2 col-groups; TERMS=1 -> 2 x 4
    const int wr = (TERMS == 2) ? (w & 3) : (w >> 2);
    const int wc = (TERMS == 2) ? (w >> 2) : (w & 3);

    __shared__ unsigned short smem[(TERMS == 2) ? 49152 : 65536];

    const unsigned short* Ah0 = Ah_g + (long long)b * strideA + (long long)rowBase * lda;
    const unsigned short* Bh0 = Bh_g + (long long)b * strideB + (long long)colBase * ldb;
    const unsigned short* Al0 = (TERMS == 2)
        ? Al_g + (long long)b * strideA + (long long)rowBase * lda : nullptr;

    f32x4 acc[(TERMS == 2) ? 4 : 8][(TERMS == 2) ? 8 : 4] = {};
    const int NT = K / KT;

    stage_ktile<TERMS>(Ah0, Al0, lda, Bh0, ldb, 0, smem, w, lane);
    __syncthreads();

    for (int kt = 0; kt < NT; ++kt) {
        unsigned short* cbuf = smem + (kt & 1) * BUF;
        if (kt + 1 < NT)
            stage_ktile<TERMS>(Ah0, Al0, lda, Bh0, ldb, (kt + 1) * KT,
                               smem + ((kt + 1) & 1) * BUF, w, lane);

        if constexpr (TERMS == 2) {
            const unsigned short* tAh = cbuf;
            const unsigned short* tAl = cbuf + 8192;
            const unsigned short* tB  = cbuf + 16384;
            f16x8 ah[4], al[4];
#pragma unroll
            for (int i = 0; i < 4; ++i) {
                const int r = wr * 64 + i * 16 + lr;
                ah[i] = frag32(tAh, r, lg);
                al[i] = frag32(tAl, r, lg);
            }
#pragma unroll
            for (int jh = 0; jh < 2; ++jh) {
                f16x8 bh[4];
#pragma unroll
                for (int j = 0; j < 4; ++j)
                    bh[j] = frag32(tB, wc * 128 + jh * 64 + j * 16 + lr, lg);
#pragma unroll
                for (int i = 0; i < 4; ++i)
#pragma unroll
                    for (int j = 0; j < 4; ++j) {
                        f32x4 a = acc[i][jh * 4 + j];
                        a = __builtin_amdgcn_mfma_f32_16x16x32_f16(ah[i], bh[j], a, 0, 0, 0);
                        a = __builtin_amdgcn_mfma_f32_16x16x32_f16(al[i], bh[j], a, 0, 0, 0);
                        acc[i][jh * 4 + j] = a;
                    }
            }
        } else {
            const unsigned short* tA = cbuf;
            const unsigned short* tB = cbuf + 16384;
            f16x8 bh[8];
#pragma unroll
            for (int j = 0; j < 4; ++j)
#pragma unroll
                for (int ks = 0; ks < 2; ++ks)
                    bh[j * 2 + ks] = frag64(tB, wc * 64 + j * 16 + lr, ks * 4 + lg);
#pragma unroll
            for (int ih = 0; ih < 2; ++ih) {
                f16x8 ah[8];
#pragma unroll
                for (int f = 0; f < 4; ++f)
#pragma unroll
                    for (int ks = 0; ks < 2; ++ks)
                        ah[f * 2 + ks] = frag64(tA, wr * 128 + ih * 64 + f * 16 + lr, ks * 4 + lg);
#pragma unroll
                for (int f = 0; f < 4; ++f)
#pragma unroll
                    for (int j = 0; j < 4; ++j) {
                        f32x4 a = acc[ih * 4 + f][j];
                        a = __builtin_amdgcn_mfma_f32_16x16x32_f16(ah[f * 2 + 0], bh[j * 2 + 0], a, 0, 0, 0);
                        a = __builtin_amdgcn_mfma_f32_16x16x32_f16(ah[f * 2 + 1], bh[j * 2 + 1], a, 0, 0, 0);
                        acc[ih * 4 + f][j] = a;
                    }
            }
        }
        __syncthreads();
    }

    // ---- epilogue: per-wave private LDS bounce (8KB each), no interior barriers ----
    __syncthreads();
    float* stg = reinterpret_cast<float*>(smem) + w * 2048;

    if constexpr (TERMS == 2) {
        // wave tile 64x128; 4 rounds of 16 rows x 128 cols
        const int colg0 = colBase + wc * 128;
#pragma unroll
        for (int rnd = 0; rnd < 4; ++rnd) {
            const int rowg0 = rowBase + wr * 64 + rnd * 16;
#pragma unroll
            for (int j = 0; j < 8; ++j)
#pragma unroll
                for (int r2 = 0; r2 < 4; ++r2)
                    stg[(lg * 4 + r2) * 128 + j * 16 + lr] = acc[rnd][j][r2];

            if constexpr (OMODE == 0) {
#pragma unroll
                for (int t = 0; t < 8; ++t) {
                    const int idx = t * 256 + lane * 4;
                    const int r = idx >> 7, c = idx & 127;
                    float4 v = *reinterpret_cast<const float4*>(&stg[idx]);
                    const int colg = colg0 + c;
                    if (mask != nullptr) {
                        const int4 mv = *reinterpret_cast<const int4*>(
                            &mask[(long long)b * strideMask + colg]);
                        v.x += NEG_INF_F * (float)mv.x;
                        v.y += NEG_INF_F * (float)mv.y;
                        v.z += NEG_INF_F * (float)mv.z;
                        v.w += NEG_INF_F * (float)mv.w;
                    }
                    *reinterpret_cast<float4*>(
                        &Cf[(long long)b * strideC + (long long)(rowg0 + r) * ldc + colg]) = v;
                }
            } else if constexpr (OMODE == 1) {
#pragma unroll
                for (int t = 0; t < 8; ++t) {
                    const int idx = t * 256 + lane * 4;
                    const int r = idx >> 7, c = idx & 127;
                    const float4 v = *reinterpret_cast<const float4*>(&stg[idx]);
                    ushort4 h, l;
                    h.x = f16_of(v.x); l.x = f16_of(v.x - f32_of(h.x));
                    h.y = f16_of(v.y); l.y = f16_of(v.y - f32_of(h.y));
                    h.z = f16_of(v.z); l.z = f16_of(v.z - f32_of(h.z));
                    h.w = f16_of(v.w); l.w = f16_of(v.w - f32_of(h.w));
                    const long long cidx = (long long)(rowg0 + r) * ldc + colg0 + c;
                    *reinterpret_cast<ushort4*>(&Ch[cidx]) = h;
                    *reinterpret_cast<ushort4*>(&Cl[cidx]) = l;
                }
            } else {  // OMODE == 2
#pragma unroll
                for (int t = 0; t < 8; ++t) {
                    const int idx = t * 256 + lane * 4;
                    const int r = idx >> 7, c = idx & 127;
                    const float4 v = *reinterpret_cast<const float4*>(&stg[idx]);
                    ushort4 h;
                    h.x = f16_of(v.x); h.y = f16_of(v.y);
                    h.z = f16_of(v.z); h.w = f16_of(v.w);
                    *reinterpret_cast<ushort4*>(
                        &Ch[(long long)(rowg0 + r) * ldc + colg0 + c]) = h;
                }
            }
        }
    } else {
        // wave tile 128x64; 4 rounds of 32 rows x 64 cols
        const int colg0 = colBase + wc * 64;
#pragma unroll
        for (int rnd = 0; rnd < 4; ++rnd) {
            const int rowg0 = rowBase + wr * 128 + rnd * 32;
#pragma unroll
            for (int ii = 0; ii < 2; ++ii)
#pragma unroll
                for (int j = 0; j < 4; ++j)
#pragma unroll
                    for (int r2 = 0; r2 < 4; ++r2)
                        stg[(ii * 16 + lg * 4 + r2) * 64 + j * 16 + lr] = acc[rnd * 2 + ii][j][r2];

            if constexpr (OMODE == 0) {
#pragma unroll
                for (int t = 0; t < 8; ++t) {
                    const int idx = t * 256 + lane * 4;
                    const int r = idx >> 6, c = idx & 63;
                    float4 v = *reinterpret_cast<const float4*>(&stg[idx]);
                    const int colg = colg0 + c;
                    if (mask != nullptr) {
                        const int4 mv = *reinterpret_cast<const int4*>(
                            &mask[(long long)b * strideMask + colg]);
                        v.x += NEG_INF_F * (float)mv.x;
                        v.y += NEG_INF_F * (float)mv.y;
                        v.z += NEG_INF_F * (float)mv.z;
                        v.w += NEG_INF_F * (float)mv.w;
                    }
                    *reinterpret_cast<float4*>(
                        &Cf[(long long)b * strideC + (long long)(rowg0 + r) * ldc + colg]) = v;
                }
            } else {  // OMODE == 3: V^T store  Ch[b2][col][s]
                const int b2 = rowg0 >> 11;
                const int s0 = rowg0 & 2047;
                const int colg = colg0 + lane;
                alignas(16) unsigned short u[32];
#pragma unroll
                for (int rr = 0; rr < 32; ++rr) u[rr] = f16_of(stg[rr * 64 + lane]);
                unsigned short* vp = Ch + (long long)b2 * (1024LL * 2048)
                                   + (long long)colg * 2048 + s0;
#pragma unroll
                for (int q = 0; q < 4; ++q)
                    *reinterpret_cast<uint4*>(vp + q * 8) =
                        *reinterpret_cast<const uint4*>(&u[q * 8]);
            }
        }
    }
}

// ---------------- helpers ----------------
// f32 -> (hi, lo) f16 split
__global__ __launch_bounds__(256) void split2_kernel(
    const float* __restrict__ in, unsigned short* __restrict__ hi,
    unsigned short* __restrict__ lo, long long n)
{
    for (long long i = ((long long)blockIdx.x * 256 + threadIdx.x) * 4; i < n;
         i += (long long)gridDim.x * 256 * 4) {
        float4 v = *reinterpret_cast<const float4*>(&in[i]);
        ushort4 h, l;
        h.x = f16_of(v.x); l.x = f16_of(v.x - f32_of(h.x));
        h.y = f16_of(v.y); l.y = f16_of(v.y - f32_of(h.y));
        h.z = f16_of(v.z); l.z = f16_of(v.z - f32_of(h.z));
        h.w = f16_of(v.w); l.w = f16_of(v.w - f32_of(h.w));
        *reinterpret_cast<ushort4*>(&hi[i]) = h;
        *reinterpret_cast<ushort4*>(&lo[i]) = l;
    }
}

// f32 [N][N] -> TRANSPOSED hi/lo f16: hi[j][i] = split(in[i][j]).  N % 64 == 0.
__global__ __launch_bounds__(256) void tsplit_kernel(
    const float* __restrict__ in, unsigned short* __restrict__ hi,
    unsigned short* __restrict__ lo, int N)
{
    __shared__ float tile[64][65];
    const int bi = blockIdx.x * 64;
    const int bj = blockIdx.y * 64;
    const int t = threadIdx.x;
    const int c4 = (t & 15) * 4;
    const int r0 = (t >> 4) * 4;
#pragma unroll
    for (int rr = 0; rr < 4; ++rr) {
        float4 v = *reinterpret_cast<const float4*>(
            &in[(long long)(bi + r0 + rr) * N + bj + c4]);
        tile[r0 + rr][c4 + 0] = v.x;
        tile[r0 + rr][c4 + 1] = v.y;
        tile[r0 + rr][c4 + 2] = v.z;
        tile[r0 + rr][c4 + 3] = v.w;
    }
    __syncthreads();
    const int oc  = t >> 2;
    const int or0 = (t & 3) * 16;
    alignas(16) unsigned short uh[16], ul[16];
#pragma unroll
    for (int e = 0; e < 16; ++e) {
        const float f = tile[or0 + e][oc];
        const unsigned short h = f16_of(f);
        uh[e] = h;
        ul[e] = f16_of(f - f32_of(h));
    }
    unsigned short* hp = hi + (long long)(bj + oc) * N + bi + or0;
    unsigned short* lp = lo + (long long)(bj + oc) * N + bi + or0;
    *reinterpret_cast<uint4*>(hp)     = *reinterpret_cast<const uint4*>(&uh[0]);
    *reinterpret_cast<uint4*>(hp + 8) = *reinterpret_cast<const uint4*>(&uh[8]);
    *reinterpret_cast<uint4*>(lp)     = *reinterpret_cast<const uint4*>(&ul[0]);
    *reinterpret_cast<uint4*>(lp + 8) = *reinterpret_cast<const uint4*>(&ul[8]);
}

// f32 -> f16
__global__ __launch_bounds__(256) void cvt_kernel(
    const float* __restrict__ in, unsigned short* __restrict__ out, long long n)
{
    for (long long i = ((long long)blockIdx.x * 256 + threadIdx.x) * 4; i < n;
         i += (long long)gridDim.x * 256 * 4) {
        float4 v = *reinterpret_cast<const float4*>(&in[i]);
        ushort4 h;
        h.x = f16_of(v.x); h.y = f16_of(v.y); h.z = f16_of(v.z); h.w = f16_of(v.w);
        *reinterpret_cast<ushort4*>(&out[i]) = h;
    }
}

// In-place f32 row softmax (rows=16384, cols=2048) + f16 copy for PV.
__global__ __launch_bounds__(256) void softmax_kernel(
    float* __restrict__ s, unsigned short* __restrict__ p)
{
    const long long row = blockIdx.x;
    float* sp = s + row * 2048;
    const int tid = threadIdx.x;

    float v[8];
    *reinterpret_cast<float4*>(&v[0]) = *reinterpret_cast<const float4*>(&sp[tid * 8]);
    *reinterpret_cast<float4*>(&v[4]) = *reinterpret_cast<const float4*>(&sp[tid * 8 + 4]);

    float m = v[0];
#pragma unroll
    for (int i = 1; i < 8; ++i) m = fmaxf(m, v[i]);
#pragma unroll
    for (int off = 1; off < 64; off <<= 1) m = fmaxf(m, __shfl_xor(m, off));

    __shared__ float redm[4];
    __shared__ float reds[4];
    if ((tid & 63) == 0) redm[tid >> 6] = m;
    __syncthreads();
    m = fmaxf(fmaxf(redm[0], redm[1]), fmaxf(redm[2], redm[3]));

    float sum = 0.f;
#pragma unroll
    for (int i = 0; i < 8; ++i) {
        v[i] = __expf(v[i] - m);
        sum += v[i];
    }
#pragma unroll
    for (int off = 1; off < 64; off <<= 1) sum += __shfl_xor(sum, off);
    if ((tid & 63) == 0) reds[tid >> 6] = sum;
    __syncthreads();
    sum = reds[0] + reds[1] + reds[2] + reds[3];

    const float inv = 1.0f / sum;
#pragma unroll
    for (int i = 0; i < 8; ++i) v[i] *= inv;

    *reinterpret_cast<float4*>(&sp[tid * 8])     = *reinterpret_cast<const float4*>(&v[0]);
    *reinterpret_cast<float4*>(&sp[tid * 8 + 4]) = *reinterpret_cast<const float4*>(&v[4]);

    ushort4 o0, o1;
    o0.x = f16_of(v[0]); o0.y = f16_of(v[1]); o0.z = f16_of(v[2]); o0.w = f16_of(v[3]);
    o1.x = f16_of(v[4]); o1.y = f16_of(v[5]); o1.z = f16_of(v[6]); o1.w = f16_of(v[7]);
    *reinterpret_cast<ushort4*>(&p[row * 2048 + tid * 8])     = o0;
    *reinterpret_cast<ushort4*>(&p[row * 2048 + tid * 8 + 4]) = o1;
}

extern "C" void kernel_launch(void* const* d_in, const int* in_sizes, int n_in,
                              void* d_out, int out_size, void* d_ws, size_t ws_size,
                              hipStream_t stream)
{
    (void)in_sizes; (void)n_in; (void)out_size; (void)ws_size;

    const int S = 2048, D = 1024;
    const long long BS  = 8LL * S;          // 16384
    const long long SD  = (long long)S * D;
    const long long SS  = (long long)S * S;
    const long long BSD = BS * D;
    const long long DD  = (long long)D * D;

    const float* x    = (const float*)d_in[0];
    const int*   mask = (const int*)d_in[1];
    const float* wq   = (const float*)d_in[2];
    const float* wk   = (const float*)d_in[3];
    const float* wv   = (const float*)d_in[4];

    float* out = (float*)d_out;             // [BS, D] f32 (final)
    float* s   = out + BSD;                 // [B, S, S] f32 (final)

    // ws layout (halves):
    //   Gh [16384][1024] | Gl [16384][1024]   (later overwritten by p [B][S][S])
    //   Vt [B][D][S] | wvh | Mth
    unsigned short* Gh  = (unsigned short*)d_ws;
    unsigned short* Gl  = Gh + BSD;
    unsigned short* p   = Gh;               // 2*BSD halves, overwrites Gh+Gl
    unsigned short* Vt  = Gh + 2 * BSD;
    unsigned short* wvh = Gh + 3 * BSD;
    unsigned short* Mth = wvh + DD;

    // x split lives in d_out's out-region until PV overwrites it
    unsigned short* xh = (unsigned short*)out;
    unsigned short* xl = xh + BSD;
    // transposed weight splits live in d_out's s-region until scores overwrites it
    unsigned short* wqTh = (unsigned short*)s;   // [1024][1024] = wq^T hi
    unsigned short* wqTl = wqTh + DD;
    unsigned short* wkTh = wqTl + DD;
    unsigned short* wkTl = wkTh + DD;

    dim3 blk256(256), blk512(512);

    split2_kernel<<<dim3(2048), blk256, 0, stream>>>(x, xh, xl, BSD);
    tsplit_kernel<<<dim3(16, 16), blk256, 0, stream>>>(wq, wqTh, wqTl, D);
    tsplit_kernel<<<dim3(16, 16), blk256, 0, stream>>>(wk, wkTh, wkTl, D);

    // Mt[j][i] = sum_e wk[e][j]*wq[e][i]; A = (wkTh,wkTl) split, B = wqTh, plain f16 out
    mfma_gemm256<2, 2><<<dim3(4, 4, 1), blk512, 0, stream>>>(
        wkTh, wkTl, 0, D, wqTh, 0, D,
        nullptr, Mth, nullptr, 0, D, D, nullptr, 0);

    // G = x @ Mt^T: A = (xh,xl) split, B = Mth; split-f16 out (Gh,Gl)
    mfma_gemm256<2, 1><<<dim3(64, 4, 1), blk512, 0, stream>>>(
        xh, xl, 0, D, Mth, 0, D,
        nullptr, Gh, Gl, 0, D, D, nullptr, 0);

    // scores = G @ x^T + NEG_INF*mask: A = (Gh,Gl) split, B = xh; f32 out
    mfma_gemm256<2, 0><<<dim3(8, 8, 8), blk512, 0, stream>>>(
        Gh, Gl, SD, D, xh, SD, D,
        s, nullptr, nullptr, SS, S, D, mask, S);

    // softmax in place + f16 p for PV (p overwrites Gh/Gl)
    softmax_kernel<<<dim3(16384), blk256, 0, stream>>>(s, p);

    // wv -> f16, then V^T = (x @ wv^T)^T directly (1-term, transposed store)
    cvt_kernel<<<dim3(512), blk256, 0, stream>>>(wv, wvh, DD);
    mfma_gemm256<1, 3><<<dim3(64, 4, 1), blk512, 0, stream>>>(
        xh, nullptr, 0, D, wvh, 0, D,
        nullptr, Vt, nullptr, 0, 0, D, nullptr, 0);

    // out = p @ V = p @ (V^T)^T  (1-term BK=64, NT form, f32 out)
    mfma_gemm256<1, 0><<<dim3(8, 4, 8), blk512, 0, stream>>>(
        p, nullptr, SS, S, Vt, SD, S,
        out, nullptr, nullptr, SD, D, S, nullptr, 0);
}